// Round 1
// 939.396 us; speedup vs baseline: 1.0600x; 1.0600x over previous
//
#include <hip/hip_runtime.h>
#include <math.h>

#define B_ 256
#define S_ 512
#define K_ 20
#define D_ 256
#define NT 512
#define LDH 264   // bf16 LDS row stride (shorts), 16B-aligned rows, bank-spread

typedef __attribute__((ext_vector_type(8))) short short8;
typedef __attribute__((ext_vector_type(4))) short short4v;
typedef __attribute__((ext_vector_type(4))) float f32x4;

__device__ __forceinline__ unsigned short rne_bf16(float f) {
  unsigned u = __builtin_bit_cast(unsigned, f);
  u += 0x7FFFu + ((u >> 16) & 1u);
  return (unsigned short)(u >> 16);
}
__device__ __forceinline__ float bf16_to_f32(unsigned short h) {
  return __builtin_bit_cast(float, ((unsigned)h) << 16);
}

// Fully fused: per-batch block computes compact XW (active rows only) in its
// prologue, then runs the recurrence with double-buffered LDS state so the
// main loop needs only ONE __syncthreads per step (was two).
__global__ __launch_bounds__(NT, 2)
void rnn_fused8(const float* __restrict__ es, const int* __restrict__ mask,
                const float* __restrict__ keys, const float* __restrict__ U,
                const float* __restrict__ V, const float* __restrict__ W,
                float* __restrict__ XWc, float* __restrict__ out) {
  __shared__ unsigned short sH0[32 * LDH];  // buf 0 (prologue: hi staging)
  __shared__ unsigned short sH1[32 * LDH];  // buf 1 (prologue: lo staging)
  __shared__ float sRed[2][3][K_][9];       // double-buffered partials
  __shared__ float sLam[32];
  __shared__ short sAct[S_];
  __shared__ int   sNact;

  const int b = blockIdx.x, t = threadIdx.x;
  const int w = t >> 6, lane = t & 63, quad = lane >> 4, n = lane & 15;
  const int e0a = (w << 5) + quad * 4;

  // ---- P0: zero both sRed buffers; build compact active-step list ----
  for (int i = t; i < 2 * 3 * K_ * 9; i += NT) ((float*)sRed)[i] = 0.0f;
  if (w == 0) {
    int base = 0;
    for (int c = 0; c < 8; ++c) {
      int s = c * 64 + lane;
      int mv = mask[b * S_ + s];
      unsigned long long bal = __ballot(mv != 0);
      int pos = base + (int)__popcll(bal & ((1ull << lane) - 1ull));
      if (mv) sAct[pos] = (short)s;
      base += (int)__popcll(bal);
    }
    if (lane == 0) sNact = base;
  }
  __syncthreads();
  const int nAct = sNact;

  short8 aHi[8][2], aLo[8][2];  // A-frags: reused for W, then V, then U
  auto load_A = [&](const float* __restrict__ M) {
#pragma unroll
    for (int kt = 0; kt < 8; ++kt)
#pragma unroll
      for (int et = 0; et < 2; ++et) {
        const int e = ((2 * w + et) << 4) + n;
        const int d0 = kt * 32 + quad * 8;
        short8 h8, l8;
#pragma unroll
        for (int j = 0; j < 8; ++j) {
          float f = M[(d0 + j) * D_ + e];
          unsigned short hi = rne_bf16(f);
          h8[j] = (short)hi;
          l8[j] = (short)rne_bf16(f - bf16_to_f32(hi));
        }
        aHi[kt][et] = h8; aLo[kt][et] = l8;
      }
  };
  auto run_mfma3 = [&](f32x4 acc[2][2]) {  // split-bf16 3-product (hi in sH0, lo in sH1)
#pragma unroll
    for (int kt = 0; kt < 8; ++kt) {
      short8 bhi[2], blo[2];
#pragma unroll
      for (int ke = 0; ke < 2; ++ke) {
        const int off = (ke * 16 + n) * LDH + kt * 32 + quad * 8;
        bhi[ke] = *(const short8*)&sH0[off];
        blo[ke] = *(const short8*)&sH1[off];
      }
#pragma unroll
      for (int et = 0; et < 2; ++et)
#pragma unroll
        for (int ke = 0; ke < 2; ++ke) {
          acc[et][ke] = __builtin_amdgcn_mfma_f32_16x16x32_bf16(aHi[kt][et], bhi[ke], acc[et][ke], 0, 0, 0);
          acc[et][ke] = __builtin_amdgcn_mfma_f32_16x16x32_bf16(aLo[kt][et], bhi[ke], acc[et][ke], 0, 0, 0);
          acc[et][ke] = __builtin_amdgcn_mfma_f32_16x16x32_bf16(aHi[kt][et], blo[ke], acc[et][ke], 0, 0, 0);
        }
    }
  };
  auto run_mfma2 = [&](f32x4 acc[2][2], const unsigned short* __restrict__ bp) {
#pragma unroll
    for (int kt = 0; kt < 8; ++kt) {
      short8 bhi[2];
#pragma unroll
      for (int ke = 0; ke < 2; ++ke)
        bhi[ke] = *(const short8*)&bp[(ke * 16 + n) * LDH + kt * 32 + quad * 8];
#pragma unroll
      for (int et = 0; et < 2; ++et)
#pragma unroll
        for (int ke = 0; ke < 2; ++ke) {
          acc[et][ke] = __builtin_amdgcn_mfma_f32_16x16x32_bf16(aHi[kt][et], bhi[ke], acc[et][ke], 0, 0, 0);
          acc[et][ke] = __builtin_amdgcn_mfma_f32_16x16x32_bf16(aLo[kt][et], bhi[ke], acc[et][ke], 0, 0, 0);
        }
    }
  };

  // ---- Phase XW: compact x@W for this batch's active rows -> scratch ----
  const size_t bbase = (size_t)b * S_;  // compact row base in XWc
  if (nAct > 0) {
    load_A(W);
    const int nPass = (nAct + 31) >> 5;
    for (int p = 0; p < nPass; ++p) {
      {  // stage 32 gathered es rows, split-bf16
        const int rr = t >> 4, c0 = (t & 15) * 16;
        const int ridx = p * 32 + rr;
        const int sidx = sAct[(ridx < nAct) ? ridx : (nAct - 1)];  // clamp: finite data
        const float* src = es + ((size_t)b * S_ + sidx) * D_ + c0;
#pragma unroll
        for (int h2 = 0; h2 < 2; ++h2) {
          f32x4 f0 = *(const f32x4*)(src + h2 * 8);
          f32x4 f1 = *(const f32x4*)(src + h2 * 8 + 4);
          short8 hh, ll;
#pragma unroll
          for (int j = 0; j < 4; ++j) {
            unsigned short a = rne_bf16(f0[j]);
            hh[j] = (short)a; ll[j] = (short)rne_bf16(f0[j] - bf16_to_f32(a));
            unsigned short bq = rne_bf16(f1[j]);
            hh[4 + j] = (short)bq; ll[4 + j] = (short)rne_bf16(f1[j] - bf16_to_f32(bq));
          }
          *(short8*)&sH0[rr * LDH + c0 + h2 * 8] = hh;
          *(short8*)&sH1[rr * LDH + c0 + h2 * 8] = ll;
        }
      }
      __syncthreads();
      f32x4 acc[2][2] = {};
      run_mfma3(acc);
#pragma unroll
      for (int et = 0; et < 2; ++et)
#pragma unroll
        for (int ke = 0; ke < 2; ++ke) {
          const int g = p * 32 + ke * 16 + n;
          if (g < nAct)
            *(f32x4*)&XWc[(bbase + g) * D_ + e0a + 16 * et] = acc[et][ke];
        }
      __syncthreads();  // before next pass overwrites staging
    }
  }

  // ---- zero BOTH h-buffers fully (restores ke=1 garbage-containment) ----
  for (int i = t; i < 32 * LDH; i += NT) { sH0[i] = 0; sH1[i] = 0; }
  __syncthreads();

  // ---- keys staging + kReg + V frags ----
  for (int i = t; i < K_ * D_; i += NT) {
    int k = i >> 8, d = i & 255;
    float f = keys[(b * K_ + k) * D_ + d];
    unsigned short hi = rne_bf16(f);
    sH0[k * LDH + d] = hi;
    sH1[k * LDH + d] = rne_bf16(f - bf16_to_f32(hi));
  }
  f32x4 kReg[2][2];
#pragma unroll
  for (int et = 0; et < 2; ++et)
#pragma unroll
    for (int ke = 0; ke < 2; ++ke) {
      const int k = ke * 16 + n;
#pragma unroll
      for (int r = 0; r < 4; ++r)
        kReg[et][ke][r] = (k < K_) ? keys[(size_t)(b * K_ + k) * D_ + e0a + 16 * et + r] : 0.0f;
    }
  load_A(V);
  __syncthreads();  // keys staged

  f32x4 kvReg[2][2] = {};
  run_mfma3(kvReg);
  __syncthreads();  // kV reads done

  // ---- zero state rows (both buffers), U frags, pipeline seed, pxk ----
  for (int i = t; i < K_ * LDH; i += NT) { sH0[i] = 0; sH1[i] = 0; }
  load_A(U);
  f32x4 hReg[2][2] = {};
  f32x4 xEc[2] = {}, xwEc[2] = {};
  if (nAct > 0) {
    const int s1 = sAct[(nAct > 1) ? 1 : 0];
#pragma unroll
    for (int et = 0; et < 2; ++et) {
      xEc[et]  = *(const f32x4*)&es[((size_t)b * S_ + s1) * D_ + e0a + 16 * et];
      xwEc[et] = *(const f32x4*)&XWc[bbase * D_ + e0a + 16 * et];
    }
    // pxk for step 0: x_0 . keys
    const int s0 = sAct[0];
    float p0 = 0.0f, p1 = 0.0f;
#pragma unroll
    for (int et = 0; et < 2; ++et) {
      f32x4 xq = *(const f32x4*)&es[((size_t)b * S_ + s0) * D_ + e0a + 16 * et];
#pragma unroll
      for (int r = 0; r < 4; ++r) {
        p0 = fmaf(xq[r], kReg[et][0][r], p0);
        p1 = fmaf(xq[r], kReg[et][1][r], p1);
      }
    }
    p0 += __shfl_xor(p0, 16, 64); p0 += __shfl_xor(p0, 32, 64);
    p1 += __shfl_xor(p1, 16, 64); p1 += __shfl_xor(p1, 32, 64);
    if (quad == 0) {
      sRed[0][2][n][w] = p0;
      if (n < 4) sRed[0][2][16 + n][w] = p1;
    }
  }
  __syncthreads();  // everything ready for step 0

  // ---- recurrence: ONE barrier per step (double-buffered sH / sRed) ----
  for (int i = 0; i < nAct; ++i) {
    const int rb = i & 1, wbuf = rb ^ 1;
    const unsigned short* bR = rb ? sH1 : sH0;   // read: state written step i-1
    unsigned short* bW = rb ? sH0 : sH1;         // write: state for step i+1

    // issue next-slot global loads (consumed in epilogue of step i+1)
    const int iX = (i + 2 < nAct) ? i + 2 : nAct - 1;
    const int iW = (i + 1 < nAct) ? i + 1 : nAct - 1;
    const size_t rX = ((size_t)b * S_ + sAct[iX]) * D_;
    f32x4 xEn[2], xwEn[2];
#pragma unroll
    for (int et = 0; et < 2; ++et) {
      xEn[et]  = *(const f32x4*)&es[rX + e0a + 16 * et];
      xwEn[et] = *(const f32x4*)&XWc[(bbase + iW) * D_ + e0a + 16 * et];
    }

    // lam/g redundantly per wave (lanes 0..19), from previous step's partials
    float lamv = 0.0f, gv = 0.0f;
    if (lane < K_) {
      float ss = 0.0f, xh = 0.0f, xk = 0.0f;
#pragma unroll
      for (int j = 0; j < 8; ++j) {
        ss += sRed[rb][0][lane][j]; xh += sRed[rb][1][lane][j]; xk += sRed[rb][2][lane][j];
      }
      lamv = rsqrtf(fmaxf(ss, 1e-12f));
      gv = 1.0f / (1.0f + expf(-(lamv * xh + xk)));
    }
    const float lm0 = __shfl(lamv, n, 64);
    const float g0 = __shfl(gv, n, 64);
    const float lm1s = __shfl(lamv, 16 + n, 64);
    const float g1s = __shfl(gv, 16 + n, 64);

    f32x4 acc[2][2] = {};
    run_mfma2(acc, bR);

    const float lm1 = (n < 4) ? lm1s : 0.0f;
    const float g1 = (n < 4) ? g1s : 0.0f;
    float psq0 = 0.0f, psq1 = 0.0f, pxh0 = 0.0f, pxh1 = 0.0f, pxk0 = 0.0f, pxk1 = 0.0f;
#pragma unroll
    for (int et = 0; et < 2; ++et) {
      const int e0 = e0a + 16 * et;
      f32x4 xw4 = xwEc[et];
      f32x4 xn4 = xEc[et];
      {  // ke=0
        f32x4 u; short4v hh;
#pragma unroll
        for (int r = 0; r < 4; ++r) {
          float T = fmaxf(fmaf(lm0, acc[et][0][r], kvReg[et][0][r] + xw4[r]), 0.0f);
          float uv = fmaf(g0, T, lm0 * hReg[et][0][r]);
          u[r] = uv;
          psq0 = fmaf(uv, uv, psq0);
          pxh0 = fmaf(xn4[r], uv, pxh0);
          pxk0 = fmaf(xn4[r], kReg[et][0][r], pxk0);
          hh[r] = (short)rne_bf16(uv);
        }
        hReg[et][0] = u;
        *(short4v*)&bW[n * LDH + e0] = hh;
      }
      {  // ke=1
        f32x4 u; short4v hh;
#pragma unroll
        for (int r = 0; r < 4; ++r) {
          float T = fmaxf(fmaf(lm1, acc[et][1][r], kvReg[et][1][r] + xw4[r]), 0.0f);
          float uv = fmaf(g1, T, lm1 * hReg[et][1][r]);
          u[r] = uv;
          psq1 = fmaf(uv, uv, psq1);
          pxh1 = fmaf(xn4[r], uv, pxh1);
          pxk1 = fmaf(xn4[r], kReg[et][1][r], pxk1);
          hh[r] = (short)rne_bf16(uv);
        }
        hReg[et][1] = u;
        if (n < 4) *(short4v*)&bW[(16 + n) * LDH + e0] = hh;
      }
    }
    psq0 += __shfl_xor(psq0, 16, 64); psq0 += __shfl_xor(psq0, 32, 64);
    pxh0 += __shfl_xor(pxh0, 16, 64); pxh0 += __shfl_xor(pxh0, 32, 64);
    pxk0 += __shfl_xor(pxk0, 16, 64); pxk0 += __shfl_xor(pxk0, 32, 64);
    psq1 += __shfl_xor(psq1, 16, 64); psq1 += __shfl_xor(psq1, 32, 64);
    pxh1 += __shfl_xor(pxh1, 16, 64); pxh1 += __shfl_xor(pxh1, 32, 64);
    pxk1 += __shfl_xor(pxk1, 16, 64); pxk1 += __shfl_xor(pxk1, 32, 64);
    if (quad == 0) {
      sRed[wbuf][0][n][w] = psq0; sRed[wbuf][1][n][w] = pxh0; sRed[wbuf][2][n][w] = pxk0;
      if (n < 4) {
        sRed[wbuf][0][16 + n][w] = psq1; sRed[wbuf][1][16 + n][w] = pxh1; sRed[wbuf][2][16 + n][w] = pxk1;
      }
    }
#pragma unroll
    for (int et = 0; et < 2; ++et) { xEc[et] = xEn[et]; xwEc[et] = xwEn[et]; }
    __syncthreads();  // the only per-step barrier
  }

  // ---- final lam + emit ----
  const int fb = nAct & 1;  // buffer written by last step (or zeros if nAct==0)
  if (t < K_) {
    float ss = 0.0f;
#pragma unroll
    for (int j = 0; j < 8; ++j) ss += sRed[fb][0][t][j];
    sLam[t] = rsqrtf(fmaxf(ss, 1e-12f));
  }
  __syncthreads();
#pragma unroll
  for (int et = 0; et < 2; ++et)
#pragma unroll
    for (int ke = 0; ke < 2; ++ke) {
      const int k = ke * 16 + n;
      if (k < K_) {
        const float lm = sLam[k];
        const int e0 = e0a + 16 * et;
        f32x4 o;
#pragma unroll
        for (int r = 0; r < 4; ++r) o[r] = lm * hReg[et][ke][r];
        *(f32x4*)&out[(size_t)(b * K_ + k) * D_ + e0] = o;
      }
    }
}

extern "C" void kernel_launch(void* const* d_in, const int* in_sizes, int n_in,
                              void* d_out, int out_size, void* d_ws, size_t ws_size,
                              hipStream_t stream) {
  const float* es   = (const float*)d_in[0];
  const int*   mask = (const int*)d_in[1];
  const float* keys = (const float*)d_in[2];
  const float* U    = (const float*)d_in[3];
  const float* V    = (const float*)d_in[4];
  const float* W    = (const float*)d_in[5];
  float* out = (float*)d_out;
  float* XWc = (float*)d_ws;  // compact per-block XW: 256 blocks x 512 rows x 1KB = 134 MB
  rnn_fused8<<<B_, NT, 0, stream>>>(es, mask, keys, U, V, W, XWc, out);
}

// Round 2
// 701.772 us; speedup vs baseline: 1.4190x; 1.3386x over previous
//
#include <hip/hip_runtime.h>
#include <math.h>

#define B_ 256
#define S_ 512
#define K_ 20
#define D_ 256
#define NT 512
#define LDH 264   // LDS row stride (shorts), 16B-aligned rows, bank-spread

typedef __attribute__((ext_vector_type(8))) short short8;
typedef __attribute__((ext_vector_type(4))) short short4v;
typedef __attribute__((ext_vector_type(4))) float f32x4;
typedef __attribute__((ext_vector_type(8))) _Float16 half8;

__device__ __forceinline__ unsigned short rne_bf16(float f) {
  unsigned u = __builtin_bit_cast(unsigned, f);
  u += 0x7FFFu + ((u >> 16) & 1u);
  return (unsigned short)(u >> 16);
}
__device__ __forceinline__ float bf16_to_f32(unsigned short h) {
  return __builtin_bit_cast(float, ((unsigned)h) << 16);
}
__device__ __forceinline__ short f16_bits(float f) {
  return (short)__builtin_bit_cast(unsigned short, (_Float16)f);  // v_cvt_f16_f32, RNE
}

// Fused kernel. Prologue (XW GEMM, kV) in proven split-bf16 3-product form.
// Recurrence hU path switched to fp16 state + fp16 U single-product:
// halves per-step MFMA (2484->1242 cy/SIMD) AND improves precision
// (state quant 2^-9 -> 2^-11, which dominated absmax).
__global__ __launch_bounds__(NT, 2)
void rnn_fused9(const float* __restrict__ es, const int* __restrict__ mask,
                const float* __restrict__ keys, const float* __restrict__ U,
                const float* __restrict__ V, const float* __restrict__ W,
                float* __restrict__ XWc, float* __restrict__ out) {
  __shared__ unsigned short sH0[32 * LDH];  // state buf 0 (prologue: hi staging)
  __shared__ unsigned short sH1[32 * LDH];  // state buf 1 (prologue: lo staging)
  __shared__ float sRed[2][3][K_][9];       // double-buffered partials
  __shared__ float sLam[32];
  __shared__ short sAct[S_];
  __shared__ int   sNact;

  const int b = blockIdx.x, t = threadIdx.x;
  const int w = t >> 6, lane = t & 63, quad = lane >> 4, n = lane & 15;
  const int e0a = (w << 5) + quad * 4;

  // ---- P0: zero sRed; build compact active-step list ----
  for (int i = t; i < 2 * 3 * K_ * 9; i += NT) ((float*)sRed)[i] = 0.0f;
  if (w == 0) {
    int base = 0;
    for (int c = 0; c < 8; ++c) {
      int s = c * 64 + lane;
      int mv = mask[b * S_ + s];
      unsigned long long bal = __ballot(mv != 0);
      int pos = base + (int)__popcll(bal & ((1ull << lane) - 1ull));
      if (mv) sAct[pos] = (short)s;
      base += (int)__popcll(bal);
    }
    if (lane == 0) sNact = base;
  }
  __syncthreads();
  const int nAct = sNact;

  short8 aHi[8][2], aLo[8][2];  // split-bf16 A-frags (W, then V)
  auto load_A = [&](const float* __restrict__ M) {
#pragma unroll
    for (int kt = 0; kt < 8; ++kt)
#pragma unroll
      for (int et = 0; et < 2; ++et) {
        const int e = ((2 * w + et) << 4) + n;
        const int d0 = kt * 32 + quad * 8;
        short8 h8, l8;
#pragma unroll
        for (int j = 0; j < 8; ++j) {
          float f = M[(d0 + j) * D_ + e];
          unsigned short hi = rne_bf16(f);
          h8[j] = (short)hi;
          l8[j] = (short)rne_bf16(f - bf16_to_f32(hi));
        }
        aHi[kt][et] = h8; aLo[kt][et] = l8;
      }
  };
  auto run_mfma3 = [&](f32x4 acc[2][2]) {  // split-bf16 3-product (hi sH0, lo sH1)
#pragma unroll
    for (int kt = 0; kt < 8; ++kt) {
      short8 bhi[2], blo[2];
#pragma unroll
      for (int ke = 0; ke < 2; ++ke) {
        const int off = (ke * 16 + n) * LDH + kt * 32 + quad * 8;
        bhi[ke] = *(const short8*)&sH0[off];
        blo[ke] = *(const short8*)&sH1[off];
      }
#pragma unroll
      for (int et = 0; et < 2; ++et)
#pragma unroll
        for (int ke = 0; ke < 2; ++ke) {
          acc[et][ke] = __builtin_amdgcn_mfma_f32_16x16x32_bf16(aHi[kt][et], bhi[ke], acc[et][ke], 0, 0, 0);
          acc[et][ke] = __builtin_amdgcn_mfma_f32_16x16x32_bf16(aLo[kt][et], bhi[ke], acc[et][ke], 0, 0, 0);
          acc[et][ke] = __builtin_amdgcn_mfma_f32_16x16x32_bf16(aHi[kt][et], blo[ke], acc[et][ke], 0, 0, 0);
        }
    }
  };

  // ---- Phase XW: compact x@W for this batch's active rows -> scratch ----
  const size_t bbase = (size_t)b * S_;
  if (nAct > 0) {
    load_A(W);
    const int nPass = (nAct + 31) >> 5;
    for (int p = 0; p < nPass; ++p) {
      {  // stage 32 gathered es rows, split-bf16
        const int rr = t >> 4, c0 = (t & 15) * 16;
        const int ridx = p * 32 + rr;
        const int sidx = sAct[(ridx < nAct) ? ridx : (nAct - 1)];
        const float* src = es + ((size_t)b * S_ + sidx) * D_ + c0;
#pragma unroll
        for (int h2 = 0; h2 < 2; ++h2) {
          f32x4 f0 = *(const f32x4*)(src + h2 * 8);
          f32x4 f1 = *(const f32x4*)(src + h2 * 8 + 4);
          short8 hh, ll;
#pragma unroll
          for (int j = 0; j < 4; ++j) {
            unsigned short a = rne_bf16(f0[j]);
            hh[j] = (short)a; ll[j] = (short)rne_bf16(f0[j] - bf16_to_f32(a));
            unsigned short bq = rne_bf16(f1[j]);
            hh[4 + j] = (short)bq; ll[4 + j] = (short)rne_bf16(f1[j] - bf16_to_f32(bq));
          }
          *(short8*)&sH0[rr * LDH + c0 + h2 * 8] = hh;
          *(short8*)&sH1[rr * LDH + c0 + h2 * 8] = ll;
        }
      }
      __syncthreads();
      f32x4 acc[2][2] = {};
      run_mfma3(acc);
#pragma unroll
      for (int et = 0; et < 2; ++et)
#pragma unroll
        for (int ke = 0; ke < 2; ++ke) {
          const int g = p * 32 + ke * 16 + n;
          if (g < nAct)
            *(f32x4*)&XWc[(bbase + g) * D_ + e0a + 16 * et] = acc[et][ke];
        }
      __syncthreads();
    }
  }

  // ---- zero BOTH buffers fully (rows 20..31 + pads stay 0 afterwards) ----
  for (int i = t; i < 32 * LDH; i += NT) { sH0[i] = 0; sH1[i] = 0; }
  __syncthreads();

  // ---- keys staging (split-bf16) + kReg + V frags ----
  for (int i = t; i < K_ * D_; i += NT) {
    int k = i >> 8, d = i & 255;
    float f = keys[(b * K_ + k) * D_ + d];
    unsigned short hi = rne_bf16(f);
    sH0[k * LDH + d] = hi;
    sH1[k * LDH + d] = rne_bf16(f - bf16_to_f32(hi));
  }
  f32x4 kReg[2][2];
#pragma unroll
  for (int et = 0; et < 2; ++et)
#pragma unroll
    for (int ke = 0; ke < 2; ++ke) {
      const int k = ke * 16 + n;
#pragma unroll
      for (int r = 0; r < 4; ++r)
        kReg[et][ke][r] = (k < K_) ? keys[(size_t)(b * K_ + k) * D_ + e0a + 16 * et + r] : 0.0f;
    }
  load_A(V);
  __syncthreads();

  f32x4 kvReg[2][2] = {};
  run_mfma3(kvReg);
  __syncthreads();  // kV reads done

  // ---- zero state rows (both buffers); load U as fp16 frags ----
  for (int i = t; i < K_ * LDH; i += NT) { sH0[i] = 0; sH1[i] = 0; }
  short8 aU[8][2];  // fp16 U^T frags (single product in the loop)
#pragma unroll
  for (int kt = 0; kt < 8; ++kt)
#pragma unroll
    for (int et = 0; et < 2; ++et) {
      const int e = ((2 * w + et) << 4) + n;
      const int d0 = kt * 32 + quad * 8;
      short8 h8;
#pragma unroll
      for (int j = 0; j < 8; ++j) h8[j] = f16_bits(U[(d0 + j) * D_ + e]);
      aU[kt][et] = h8;
    }
  auto run_mfma1 = [&](f32x4 acc[2][2], const unsigned short* __restrict__ bp) {
#pragma unroll
    for (int kt = 0; kt < 8; ++kt) {
      half8 bq[2];
#pragma unroll
      for (int ke = 0; ke < 2; ++ke)
        bq[ke] = __builtin_bit_cast(half8, *(const short8*)&bp[(ke * 16 + n) * LDH + kt * 32 + quad * 8]);
#pragma unroll
      for (int et = 0; et < 2; ++et) {
        half8 aq = __builtin_bit_cast(half8, aU[kt][et]);
#pragma unroll
        for (int ke = 0; ke < 2; ++ke)
          acc[et][ke] = __builtin_amdgcn_mfma_f32_16x16x32_f16(aq, bq[ke], acc[et][ke], 0, 0, 0);
      }
    }
  };

  f32x4 hReg[2][2] = {};
  f32x4 xEc[2] = {}, xwEc[2] = {};
  if (nAct > 0) {
    const int s1 = sAct[(nAct > 1) ? 1 : 0];
#pragma unroll
    for (int et = 0; et < 2; ++et) {
      xEc[et]  = *(const f32x4*)&es[((size_t)b * S_ + s1) * D_ + e0a + 16 * et];
      xwEc[et] = *(const f32x4*)&XWc[bbase * D_ + e0a + 16 * et];
    }
    // pxk for step 0: x_0 . keys
    const int s0 = sAct[0];
    float p0 = 0.0f, p1 = 0.0f;
#pragma unroll
    for (int et = 0; et < 2; ++et) {
      f32x4 xq = *(const f32x4*)&es[((size_t)b * S_ + s0) * D_ + e0a + 16 * et];
#pragma unroll
      for (int r = 0; r < 4; ++r) {
        p0 = fmaf(xq[r], kReg[et][0][r], p0);
        p1 = fmaf(xq[r], kReg[et][1][r], p1);
      }
    }
    p0 += __shfl_xor(p0, 16, 64); p0 += __shfl_xor(p0, 32, 64);
    p1 += __shfl_xor(p1, 16, 64); p1 += __shfl_xor(p1, 32, 64);
    if (quad == 0) {
      sRed[0][2][n][w] = p0;
      if (n < 4) sRed[0][2][16 + n][w] = p1;
    }
  }
  __syncthreads();  // ready for step 0

  // cross-half swap on VALU pipe (replaces ds_bpermute shfl_xor 32):
  // after swap: a+b holds total0 in lanes 0..31, total1 in lanes 32..63.
  auto xswap = [](float& a, float& b) {
    asm("v_permlane32_swap_b32 %0, %1" : "+v"(a), "+v"(b));
  };

  // ---- recurrence: one barrier per step, fp16 single-product hU ----
  for (int i = 0; i < nAct; ++i) {
    const int rb = i & 1, wbuf = rb ^ 1;
    const unsigned short* bR = rb ? sH1 : sH0;
    unsigned short* bW = rb ? sH0 : sH1;

    // next-slot global loads (consumed in epilogue of step i+1)
    const int iX = (i + 2 < nAct) ? i + 2 : nAct - 1;
    const int iW = (i + 1 < nAct) ? i + 1 : nAct - 1;
    const size_t rX = ((size_t)b * S_ + sAct[iX]) * D_;
    f32x4 xEn[2], xwEn[2];
#pragma unroll
    for (int et = 0; et < 2; ++et) {
      xEn[et]  = *(const f32x4*)&es[rX + e0a + 16 * et];
      xwEn[et] = *(const f32x4*)&XWc[(bbase + iW) * D_ + e0a + 16 * et];
    }

    // lam/g redundantly per wave (lanes 0..19)
    float lamv = 0.0f, gv = 0.0f;
    if (lane < K_) {
      float ss = 0.0f, xh = 0.0f, xk = 0.0f;
#pragma unroll
      for (int j = 0; j < 8; ++j) {
        ss += sRed[rb][0][lane][j]; xh += sRed[rb][1][lane][j]; xk += sRed[rb][2][lane][j];
      }
      lamv = rsqrtf(fmaxf(ss, 1e-12f));
      gv = 1.0f / (1.0f + expf(-(lamv * xh + xk)));
    }
    const float lm0 = __shfl(lamv, n, 64);
    const float g0 = __shfl(gv, n, 64);
    const float lm1s = __shfl(lamv, 16 + n, 64);
    const float g1s = __shfl(gv, 16 + n, 64);

    f32x4 acc[2][2] = {};
    run_mfma1(acc, bR);

    const float lm1 = (n < 4) ? lm1s : 0.0f;
    const float g1 = (n < 4) ? g1s : 0.0f;
    float psq0 = 0.0f, psq1 = 0.0f, pxh0 = 0.0f, pxh1 = 0.0f, pxk0 = 0.0f, pxk1 = 0.0f;
#pragma unroll
    for (int et = 0; et < 2; ++et) {
      const int e0 = e0a + 16 * et;
      f32x4 xw4 = xwEc[et];
      f32x4 xn4 = xEc[et];
      {  // ke=0
        f32x4 u; short4v hh;
#pragma unroll
        for (int r = 0; r < 4; ++r) {
          float T = fmaxf(fmaf(lm0, acc[et][0][r], kvReg[et][0][r] + xw4[r]), 0.0f);
          float uv = fmaf(g0, T, lm0 * hReg[et][0][r]);
          u[r] = uv;
          psq0 = fmaf(uv, uv, psq0);
          pxh0 = fmaf(xn4[r], uv, pxh0);
          pxk0 = fmaf(xn4[r], kReg[et][0][r], pxk0);
          hh[r] = f16_bits(uv);
        }
        hReg[et][0] = u;
        *(short4v*)&bW[n * LDH + e0] = hh;
      }
      {  // ke=1
        f32x4 u; short4v hh;
#pragma unroll
        for (int r = 0; r < 4; ++r) {
          float T = fmaxf(fmaf(lm1, acc[et][1][r], kvReg[et][1][r] + xw4[r]), 0.0f);
          float uv = fmaf(g1, T, lm1 * hReg[et][1][r]);
          u[r] = uv;
          psq1 = fmaf(uv, uv, psq1);
          pxh1 = fmaf(xn4[r], uv, pxh1);
          pxk1 = fmaf(xn4[r], kReg[et][1][r], pxk1);
          hh[r] = f16_bits(uv);
        }
        hReg[et][1] = u;
        if (n < 4) *(short4v*)&bW[(16 + n) * LDH + e0] = hh;
      }
    }
    // quad-pair reduce on LDS pipe; cross-half on VALU pipe via permlane swap
    psq0 += __shfl_xor(psq0, 16, 64); psq1 += __shfl_xor(psq1, 16, 64);
    pxh0 += __shfl_xor(pxh0, 16, 64); pxh1 += __shfl_xor(pxh1, 16, 64);
    pxk0 += __shfl_xor(pxk0, 16, 64); pxk1 += __shfl_xor(pxk1, 16, 64);
    xswap(psq0, psq1); const float sq_s = psq0 + psq1;
    xswap(pxh0, pxh1); const float xh_s = pxh0 + pxh1;
    xswap(pxk0, pxk1); const float xk_s = pxk0 + pxk1;
    if (quad == 0) {  // lanes 0..15 hold totals for k = n
      sRed[wbuf][0][n][w] = sq_s; sRed[wbuf][1][n][w] = xh_s; sRed[wbuf][2][n][w] = xk_s;
    }
    if (quad == 2 && n < 4) {  // lanes 32..35 hold totals for k = 16+n
      sRed[wbuf][0][16 + n][w] = sq_s; sRed[wbuf][1][16 + n][w] = xh_s; sRed[wbuf][2][16 + n][w] = xk_s;
    }
#pragma unroll
    for (int et = 0; et < 2; ++et) { xEc[et] = xEn[et]; xwEc[et] = xwEn[et]; }
    __syncthreads();  // the only per-step barrier
  }

  // ---- final lam + emit ----
  const int fb = nAct & 1;
  if (t < K_) {
    float ss = 0.0f;
#pragma unroll
    for (int j = 0; j < 8; ++j) ss += sRed[fb][0][t][j];
    sLam[t] = rsqrtf(fmaxf(ss, 1e-12f));
  }
  __syncthreads();
#pragma unroll
  for (int et = 0; et < 2; ++et)
#pragma unroll
    for (int ke = 0; ke < 2; ++ke) {
      const int k = ke * 16 + n;
      if (k < K_) {
        const float lm = sLam[k];
        const int e0 = e0a + 16 * et;
        f32x4 o;
#pragma unroll
        for (int r = 0; r < 4; ++r) o[r] = lm * hReg[et][ke][r];
        *(f32x4*)&out[(size_t)(b * K_ + k) * D_ + e0] = o;
      }
    }
}

extern "C" void kernel_launch(void* const* d_in, const int* in_sizes, int n_in,
                              void* d_out, int out_size, void* d_ws, size_t ws_size,
                              hipStream_t stream) {
  const float* es   = (const float*)d_in[0];
  const int*   mask = (const int*)d_in[1];
  const float* keys = (const float*)d_in[2];
  const float* U    = (const float*)d_in[3];
  const float* V    = (const float*)d_in[4];
  const float* W    = (const float*)d_in[5];
  float* out = (float*)d_out;
  float* XWc = (float*)d_ws;  // compact per-block XW: 256 x 512 x 1KB = 128 MiB
  rnn_fused9<<<B_, NT, 0, stream>>>(es, mask, keys, U, V, W, XWc, out);
}